// Round 10
// baseline (474.047 us; speedup 1.0000x reference)
//
#include <hip/hip_runtime.h>

#define NP 50000
#define NU 100000
#define NS 20000
#define NTOT 170000
#define E0 400000
#define E1 300000
#define E2 300000

typedef _Float16 f16;
typedef __attribute__((ext_vector_type(8))) _Float16 half8;
typedef __attribute__((ext_vector_type(4))) _Float16 half4;
typedef __attribute__((ext_vector_type(4))) float f32x4;
typedef unsigned int uint32;

// ---------------------------------------------------------------------------
// fused init v2: block = 64 nodes (type-pure ranges), thread = 4 dims x 8
// nodes; lin_w held in registers (20 x float4), x staged via LDS (broadcast).
// ---------------------------------------------------------------------------
#define IB0 782    // ceil(NP/64)
#define IB1 1563   // ceil(NU/64)
#define IB2 313    // ceil(NS/64)
__global__ __launch_bounds__(256) void k_init_all(
    const float* __restrict__ xp, const float* __restrict__ xu,
    const float* __restrict__ xs, const int* __restrict__ nidp,
    const int* __restrict__ nidu, const int* __restrict__ nids,
    const float* __restrict__ lin_w, const float* __restrict__ lin_b,
    const float* __restrict__ embp, const float* __restrict__ embu,
    const float* __restrict__ embs, f16* __restrict__ xb) {
  __shared__ float xl[64 * 20];  // 5 KB
  int bid = blockIdx.x, tid = threadIdx.x;
  int t, base, M, goff;
  const float* x;
  const int* nid;
  const float* emb;
  if (bid < IB0) { t = 0; base = bid * 64; M = NP; goff = 0; x = xp; nid = nidp; emb = embp; }
  else if (bid < IB0 + IB1) { t = 1; base = (bid - IB0) * 64; M = NU; goff = NP; x = xu; nid = nidu; emb = embu; }
  else { t = 2; base = (bid - IB0 - IB1) * 64; M = NS; goff = NP + NU; x = xs; nid = nids; emb = embs; }

  // stage x rows for the block's 64 nodes
#pragma unroll
  for (int i = 0; i < 5; ++i) {
    int idx = i * 256 + tid;  // 0..1279
    int nn = idx / 20, jj = idx - nn * 20;
    int gn = base + nn;
    if (gn >= M) gn = M - 1;
    xl[idx] = x[gn * 20 + jj];
  }
  __syncthreads();

  int dg = tid & 31, ns = tid >> 5;
  int d = dg * 4;
  const float* lw = lin_w + t * 20 * 128 + d;
  float4 w[20];
#pragma unroll
  for (int j = 0; j < 20; ++j) w[j] = *(const float4*)(lw + j * 128);
  float4 bb = *(const float4*)&lin_b[t * 128 + d];

#pragma unroll 2
  for (int i = 0; i < 8; ++i) {
    int ln = i * 8 + ns;
    int gn = base + ln;
    bool ok = gn < M;
    int gnc = ok ? gn : M - 1;
    float4 s = *(const float4*)&emb[(size_t)nid[gnc] * 128 + d];
    s.x += bb.x; s.y += bb.y; s.z += bb.z; s.w += bb.w;
#pragma unroll
    for (int j = 0; j < 20; ++j) {
      float xj = xl[ln * 20 + j];
      s.x += xj * w[j].x; s.y += xj * w[j].y; s.z += xj * w[j].z; s.w += xj * w[j].w;
    }
    if (ok) {
      half4 o;
      o[0] = (f16)s.x; o[1] = (f16)s.y; o[2] = (f16)s.z; o[3] = (f16)s.w;
      *(half4*)(xb + (size_t)(goff + gn) * 128 + d) = o;
    }
  }
}

// ---------------------------------------------------------------------------
// batched Keff: y = l*3+t.  Keff[y][c][d] = sum_f Wk[c][f] * We[d][f]
// ---------------------------------------------------------------------------
__global__ __launch_bounds__(128) void k_keff(const float* __restrict__ qkv_w,
                                              const float* __restrict__ qkv_b,
                                              const float* __restrict__ W_edge,
                                              float* __restrict__ Keff,
                                              float* __restrict__ bkeff) {
  int y = blockIdx.y;  // l*3 + t
  int l = y / 3, t = y - l * 3;
  int et = (t == 0) ? 0 : (t == 1) ? 2 : 1;  // edge type with dst == t
  const float* Wk = qkv_w + (size_t)(y * 3 + 1) * 16384;
  const float* bk = qkv_b + (size_t)(y * 3 + 1) * 128;
  const float* We = W_edge + (size_t)(l * 3 + et) * 16384;
  float* Ko = Keff + (size_t)y * 16384;
  float* bo = bkeff + (size_t)y * 128;

  __shared__ float Wes[128][65];
  int c = blockIdx.x, tid = threadIdx.x;
  float s = 0.f, tb = 0.f;
  for (int f0 = 0; f0 < 128; f0 += 64) {
    __syncthreads();
    int fr = tid & 63, r0 = tid >> 6;
    for (int it = 0; it < 64; ++it) {
      int row = it * 2 + r0;
      Wes[row][fr] = We[row * 128 + f0 + fr];
    }
    __syncthreads();
#pragma unroll 16
    for (int fp = 0; fp < 64; ++fp) s += Wk[c * 128 + f0 + fp] * Wes[tid][fp];
    if (c == 0) {
      for (int fp = 0; fp < 64; ++fp) tb += bk[f0 + fp] * Wes[tid][fp];
    }
  }
  Ko[c * 128 + tid] = s;
  if (c == 0) bo[tid] = tb;
}

// ---------------------------------------------------------------------------
// split+transpose all 18 weights (f16 hi/lo) in one launch.
// ---------------------------------------------------------------------------
__global__ __launch_bounds__(256) void k_splitw18(const float* __restrict__ qkv_w,
                                                  const float* __restrict__ Keff6,
                                                  f16* __restrict__ hi,
                                                  f16* __restrict__ lo) {
  int slot = blockIdx.y;
  int y = slot / 3, r = slot - y * 3;
  const float* src = (r == 1) ? (Keff6 + (size_t)y * 16384)
                              : (qkv_w + (size_t)(y * 3 + ((r == 0) ? 0 : 2)) * 16384);
  f16* h = hi + (size_t)slot * 16384;
  f16* l = lo + (size_t)slot * 16384;
  int idx = blockIdx.x * 256 + threadIdx.x;  // 0..16383
  int n = idx >> 7, c = idx & 127;
  float f = src[c * 128 + n];
  f16 hb = (f16)f;
  h[idx] = hb;
  l[idx] = (f16)(f - (float)hb);
}

// ---------------------------------------------------------------------------
// Triple-B MFMA GEMM (f16), 64-row tiles, all 3 types in one launch.
// LDS-staged A (swizzled) + LDS-staged epilogue (full-line stores).
// Q/V outputs interleaved per node: QV[node][256] = [Q | V]; K separate.
// ---------------------------------------------------------------------------
#define GB0 782    // ceil(NP/64)
#define GB1 1563   // ceil(NU/64)
#define GB2 313    // ceil(NS/64)
__global__ __launch_bounds__(256, 4) void k_gemm3(
    const f16* __restrict__ Xin,
    const f16* __restrict__ WtHi, const f16* __restrict__ WtLo,
    const float* __restrict__ qkv_b, const float* __restrict__ bkeff6,
    f16* __restrict__ QV, f16* __restrict__ Kb, int l) {
  __shared__ f16 As[64 * 128];  // 16 KB
  __shared__ f16 Ys[64 * 128];  // 16 KB output staging
  int bid = blockIdx.x;
  int t, row0, M, moff;
  if (bid < GB0) { t = 0; row0 = bid * 64; M = NP; moff = 0; }
  else if (bid < GB0 + GB1) { t = 1; row0 = (bid - GB0) * 64; M = NU; moff = NP; }
  else { t = 2; row0 = (bid - GB0 - GB1) * 64; M = NS; moff = NP + NU; }
  int y = l * 3 + t;
  const f16* A = Xin + (size_t)moff * 128;
  const f16* Whi = WtHi + (size_t)y * 3 * 16384;
  const f16* Wlo = WtLo + (size_t)y * 3 * 16384;

  int tid = threadIdx.x;
  int wave = tid >> 6, lane = tid & 63;
  int colw = wave * 32;
  int lrow = lane & 15, kgrp = lane >> 4;

  // ---- stage A tile: linear global read, swizzled LDS write ----
#pragma unroll
  for (int i = 0; i < 4; ++i) {
    int chunkLin = i * 256 + tid;  // 0..1023
    int row = chunkLin >> 4;
    int chunk = chunkLin & 15;
    int grow = row0 + row;
    if (grow >= M) grow = M - 1;
    half8 v = *(const half8*)(A + (size_t)grow * 128 + chunk * 8);
    *(half8*)(As + row * 128 + (chunk ^ (row & 7)) * 8) = v;
  }
  __syncthreads();

  int x7 = lrow & 7;

  for (int bw = 0; bw < 3; ++bw) {
    f32x4 acc[4][2] = {};
#pragma unroll
    for (int s = 0; s < 4; ++s) {
      half8 bh[2], bl[2];
#pragma unroll
      for (int nt = 0; nt < 2; ++nt) {
        int col = colw + nt * 16 + lrow;
        size_t boff = (size_t)bw * 16384 + col * 128 + s * 32 + kgrp * 8;
        bh[nt] = *(const half8*)(Whi + boff);
        bl[nt] = *(const half8*)(Wlo + boff);
      }
      int c2 = (s * 4 + kgrp) ^ x7;
#pragma unroll
      for (int mt = 0; mt < 4; ++mt) {
        int row = mt * 16 + lrow;
        half8 a = *(const half8*)(As + row * 128 + c2 * 8);
        acc[mt][0] = __builtin_amdgcn_mfma_f32_16x16x32_f16(a, bh[0], acc[mt][0], 0, 0, 0);
        acc[mt][0] = __builtin_amdgcn_mfma_f32_16x16x32_f16(a, bl[0], acc[mt][0], 0, 0, 0);
        acc[mt][1] = __builtin_amdgcn_mfma_f32_16x16x32_f16(a, bh[1], acc[mt][1], 0, 0, 0);
        acc[mt][1] = __builtin_amdgcn_mfma_f32_16x16x32_f16(a, bl[1], acc[mt][1], 0, 0, 0);
      }
    }
    // ---- epilogue: stage through LDS (swizzled), stream full lines ----
    const float* bias = (bw == 0) ? (qkv_b + (size_t)(y * 3 + 0) * 128)
                      : (bw == 1) ? (bkeff6 + (size_t)y * 128)
                                  : (qkv_b + (size_t)(y * 3 + 2) * 128);
    f16* Ybase = (bw == 1) ? Kb : (QV + ((bw == 2) ? 128 : 0));
    int RS = (bw == 1) ? 128 : 256;
    float b0 = bias[colw + lrow];
    float b1 = bias[colw + 16 + lrow];
    int col0i = colw + lrow;
    int col1i = colw + 16 + lrow;
    __syncthreads();
#pragma unroll
    for (int mt = 0; mt < 4; ++mt) {
#pragma unroll
      for (int r = 0; r < 4; ++r) {
        int lr = mt * 16 + kgrp * 4 + r;
        int sw = lr & 7;
        Ys[lr * 128 + (((col0i >> 3) ^ sw) * 8) + (col0i & 7)] = (f16)(acc[mt][0][r] + b0);
        Ys[lr * 128 + (((col1i >> 3) ^ sw) * 8) + (col1i & 7)] = (f16)(acc[mt][1][r] + b1);
      }
    }
    __syncthreads();
#pragma unroll
    for (int i = 0; i < 4; ++i) {
      int chunk = i * 256 + tid;  // 0..1023
      int row = chunk >> 4, c = chunk & 15;
      int grow = row0 + row;
      if (grow < M)
        *(half8*)(Ybase + (size_t)(moff + grow) * RS + c * 8) =
            *(const half8*)(Ys + row * 128 + ((c ^ (row & 7)) * 8));
    }
  }
}

// ---------------------------------------------------------------------------
// FUSED edge kernel: 16 lanes per dst row (4 rows/wave), 8 dims/lane.
// 2x2 software pipeline: 2 edges processed per iter, next 2 prefetched
// (clamped indices, branch-free predicated accumulate).
// ---------------------------------------------------------------------------
template <int MODE>
__global__ __launch_bounds__(256) void k_edge(
    const int* __restrict__ rowptr, const int* __restrict__ srcs,
    const f16* __restrict__ QV, const f16* __restrict__ Kb,
    f16* __restrict__ obf, float* __restrict__ of, float scale) {
  int gid = blockIdx.x * 256 + threadIdx.x;
  int wid = gid >> 4;  // dst row, one per 16-lane group
  if (wid >= NTOT) return;
  int sub = threadIdx.x & 15;  // dims sub*8 .. sub*8+7
  int dstNode, srcBase;
  if (wid < NP) { dstNode = wid; srcBase = NP; }
  else if (wid < NP + NS) { dstNode = wid + 100000; srcBase = 0; }
  else { dstNode = wid - NS; srcBase = NP + NU; }

  int s0 = rowptr[wid], s1 = rowptr[wid + 1];

  float kf[8];
  {
    half8 kh = *(const half8*)(Kb + (size_t)dstNode * 128 + sub * 8);
#pragma unroll
    for (int j = 0; j < 8; ++j) kf[j] = (float)kh[j];
  }

  float acc[8] = {};
  float dsum = 0.f;

  if (s0 < s1) {
    int last = s1 - 1;
    // preload edges s0, s0+1 (clamped)
    int kB0 = (s0 + 1 < s1) ? s0 + 1 : last;
    const f16* pA = QV + (size_t)(srcBase + srcs[s0]) * 256 + sub * 8;
    const f16* pB = QV + (size_t)(srcBase + srcs[kB0]) * 256 + sub * 8;
    half8 qA = *(const half8*)pA, vA = *(const half8*)(pA + 128);
    half8 qB = *(const half8*)pB, vB = *(const half8*)(pB + 128);

    for (int k = s0; k < s1; k += 2) {
      // prefetch edges k+2, k+3 (clamped — always legal)
      int k2 = (k + 2 < s1) ? k + 2 : last;
      int k3 = (k + 3 < s1) ? k + 3 : last;
      const f16* p2 = QV + (size_t)(srcBase + srcs[k2]) * 256 + sub * 8;
      const f16* p3 = QV + (size_t)(srcBase + srcs[k3]) * 256 + sub * 8;
      half8 nqA = *(const half8*)p2, nvA = *(const half8*)(p2 + 128);
      half8 nqB = *(const half8*)p3, nvB = *(const half8*)(p3 + 128);

      float pa = 0.f, pb = 0.f;
#pragma unroll
      for (int j = 0; j < 8; ++j) {
        pa = fmaf((float)qA[j], kf[j], pa);
        pb = fmaf((float)qB[j], kf[j], pb);
      }
      pa += __shfl_xor(pa, 8, 16); pa += __shfl_xor(pa, 4, 16);
      pa += __shfl_xor(pa, 2, 16); pa += __shfl_xor(pa, 1, 16);
      pb += __shfl_xor(pb, 8, 16); pb += __shfl_xor(pb, 4, 16);
      pb += __shfl_xor(pb, 2, 16); pb += __shfl_xor(pb, 1, 16);
      float sa = pa * scale; sa = (sa > 0.f) ? sa : 0.01f * sa;
      float sb = pb * scale; sb = (sb > 0.f) ? sb : 0.01f * sb;
      float eA = __expf(sa);
      float eB = (k + 1 < s1) ? __expf(sb) : 0.f;  // predicate tail edge
      dsum += eA + eB;
#pragma unroll
      for (int j = 0; j < 8; ++j) {
        acc[j] = fmaf((float)vA[j], eA, acc[j]);
        acc[j] = fmaf((float)vB[j], eB, acc[j]);
      }
      qA = nqA; vA = nvA; qB = nqB; vB = nvB;
    }
  }

  float inv = (s1 > s0) ? 1.f / dsum : 0.f;

  if (MODE == 0) {
    half8 o;
#pragma unroll
    for (int j = 0; j < 8; ++j) o[j] = (f16)fmaxf(acc[j] * inv, 0.f);
    *(half8*)(obf + (size_t)dstNode * 128 + sub * 8) = o;
  } else {
    float4 w0, w1;
    w0.x = acc[0] * inv; w0.y = acc[1] * inv; w0.z = acc[2] * inv; w0.w = acc[3] * inv;
    w1.x = acc[4] * inv; w1.y = acc[5] * inv; w1.z = acc[6] * inv; w1.w = acc[7] * inv;
    float* orow = of + (size_t)dstNode * 128 + sub * 8;
    *(float4*)orow = w0;
    *(float4*)(orow + 4) = w1;
  }
}

// ---------------------------------------------------------------------------
// global CSR build over all 3 edge types
// ---------------------------------------------------------------------------
__global__ void k_count_all(const int* __restrict__ e0, const int* __restrict__ e1,
                            const int* __restrict__ e2, int* __restrict__ cnt) {
  int e = blockIdx.x * 256 + threadIdx.x;
  if (e < E0) atomicAdd(&cnt[e0[E0 + e]], 1);
  else if (e < E0 + E1) atomicAdd(&cnt[NP + e1[E1 + (e - E0)]], 1);
  else if (e < E0 + E1 + E2) atomicAdd(&cnt[NP + NS + e2[E2 + (e - E0 - E1)]], 1);
}

__global__ void k_fill_all(const int* __restrict__ e0, const int* __restrict__ e1,
                           const int* __restrict__ e2, const int* __restrict__ rowptr,
                           int* __restrict__ cur, int* __restrict__ srcs) {
  int e = blockIdx.x * 256 + threadIdx.x;
  int row, src;
  if (e < E0) { row = e0[E0 + e]; src = e0[e]; }
  else if (e < E0 + E1) { row = NP + e1[E1 + (e - E0)]; src = e1[e - E0]; }
  else if (e < E0 + E1 + E2) { row = NP + NS + e2[E2 + (e - E0 - E1)]; src = e2[e - E0 - E1]; }
  else return;
  int p = atomicAdd(&cur[row], 1);
  srcs[rowptr[row] + p] = src;
}

__global__ __launch_bounds__(256) void k_blocksum(const int* __restrict__ c, int N,
                                                  int* __restrict__ bs) {
  int base = blockIdx.x * 1024;
  int t = threadIdx.x;
  int s = 0;
#pragma unroll
  for (int j = 0; j < 4; ++j) {
    int i = base + t * 4 + j;
    if (i < N) s += c[i];
  }
#pragma unroll
  for (int off = 32; off; off >>= 1) s += __shfl_down(s, off, 64);
  __shared__ int wsm[4];
  if ((t & 63) == 0) wsm[t >> 6] = s;
  __syncthreads();
  if (t == 0) bs[blockIdx.x] = wsm[0] + wsm[1] + wsm[2] + wsm[3];
}

__global__ __launch_bounds__(256) void k_scan_bsums(int* __restrict__ bs, int nb) {
  __shared__ int sm[256];
  int t = threadIdx.x;
  int v[4];
  int s = 0;
#pragma unroll
  for (int j = 0; j < 4; ++j) {
    int i = t * 4 + j;
    v[j] = (i < nb) ? bs[i] : 0;
    s += v[j];
  }
  sm[t] = s;
  __syncthreads();
  for (int off = 1; off < 256; off <<= 1) {
    int x = (t >= off) ? sm[t - off] : 0;
    __syncthreads();
    sm[t] += x;
    __syncthreads();
  }
  int run = t ? sm[t - 1] : 0;
#pragma unroll
  for (int j = 0; j < 4; ++j) {
    int i = t * 4 + j;
    if (i < nb) {
      int tmp = v[j];
      bs[i] = run;
      run += tmp;
    }
  }
}

__global__ __launch_bounds__(256) void k_scan_apply(const int* __restrict__ c,
                                                    const int* __restrict__ bofs,
                                                    int* __restrict__ rowptr, int N) {
  __shared__ int sm[256];
  int base = blockIdx.x * 1024, t = threadIdx.x;
  int v[4];
  int s = 0;
#pragma unroll
  for (int j = 0; j < 4; ++j) {
    int i = base + t * 4 + j;
    v[j] = (i < N) ? c[i] : 0;
    s += v[j];
  }
  sm[t] = s;
  __syncthreads();
  for (int off = 1; off < 256; off <<= 1) {
    int x = (t >= off) ? sm[t - off] : 0;
    __syncthreads();
    sm[t] += x;
    __syncthreads();
  }
  int run = bofs[blockIdx.x] + (t ? sm[t - 1] : 0);
#pragma unroll
  for (int j = 0; j < 4; ++j) {
    int i = base + t * 4 + j;
    if (i < N) {
      run += v[j];
      rowptr[i + 1] = run;
    }
  }
  if (blockIdx.x == 0 && t == 0) rowptr[0] = 0;
}

// ---------------------------------------------------------------------------

extern "C" void kernel_launch(void* const* d_in, const int* in_sizes, int n_in,
                              void* d_out, int out_size, void* d_ws, size_t ws_size,
                              hipStream_t stream) {
  const float* x_in[3] = {(const float*)d_in[0], (const float*)d_in[1], (const float*)d_in[2]};
  const int* nid[3] = {(const int*)d_in[3], (const int*)d_in[4], (const int*)d_in[5]};
  const int* ei[3] = {(const int*)d_in[6], (const int*)d_in[7], (const int*)d_in[8]};
  const float* lin_w = (const float*)d_in[9];
  const float* lin_b = (const float*)d_in[10];
  const float* emb[3] = {(const float*)d_in[11], (const float*)d_in[12], (const float*)d_in[13]};
  const float* qkv_w = (const float*)d_in[14];
  const float* qkv_b = (const float*)d_in[15];
  const float* W_edge = (const float*)d_in[16];
  float* out = (float*)d_out;

  char* ws = (char*)d_ws;
  size_t o = 0;
  auto carve = [&](size_t bytes) {
    char* p = ws + o;
    o = (o + bytes + 255) & ~(size_t)255;
    return p;
  };
  f16* XsA = (f16*)carve((size_t)NTOT * 128 * 2);
  f16* XsB = (f16*)carve((size_t)NTOT * 128 * 2);
  f16* QV = (f16*)carve((size_t)NTOT * 256 * 2);   // interleaved [Q|V] per node
  f16* Kb = (f16*)carve((size_t)NTOT * 128 * 2);
  float* Keff6 = (float*)carve((size_t)6 * 16384 * 4);
  float* bkeff6 = (float*)carve(6 * 128 * 4);
  f16* WtHi = (f16*)carve((size_t)18 * 16384 * 2);
  f16* WtLo = (f16*)carve((size_t)18 * 16384 * 2);
  int* cnt = (int*)carve((size_t)2 * NTOT * 4);  // cnt + cursor, one memset
  int* cur = cnt + NTOT;
  int* bsums = (int*)carve(1024 * 4);
  int* rowptr = (int*)carve((NTOT + 1) * 4);
  int* srcs = (int*)carve((size_t)(E0 + E1 + E2) * 4);
  (void)ws_size;

  // ---- initial features (single launch, w-amortized) ----
  k_init_all<<<IB0 + IB1 + IB2, 256, 0, stream>>>(
      x_in[0], x_in[1], x_in[2], nid[0], nid[1], nid[2], lin_w, lin_b, emb[0],
      emb[1], emb[2], XsA);

  // ---- global CSR over all edge types ----
  {
    const int ETOT = E0 + E1 + E2;
    int nb = (NTOT + 1023) / 1024;
    hipMemsetAsync(cnt, 0, (size_t)2 * NTOT * 4, stream);
    k_count_all<<<(ETOT + 255) / 256, 256, 0, stream>>>(ei[0], ei[1], ei[2], cnt);
    k_blocksum<<<nb, 256, 0, stream>>>(cnt, NTOT, bsums);
    k_scan_bsums<<<1, 256, 0, stream>>>(bsums, nb);
    k_scan_apply<<<nb, 256, 0, stream>>>(cnt, bsums, rowptr, NTOT);
    k_fill_all<<<(ETOT + 255) / 256, 256, 0, stream>>>(ei[0], ei[1], ei[2], rowptr, cur,
                                                       srcs);
  }

  // ---- weight prep (both layers) ----
  {
    dim3 gk(128, 6);
    k_keff<<<gk, 128, 0, stream>>>(qkv_w, qkv_b, W_edge, Keff6, bkeff6);
    dim3 gs(64, 18);
    k_splitw18<<<gs, 256, 0, stream>>>(qkv_w, Keff6, WtHi, WtLo);
  }

  const float scale = 0.08838834764831845f;  // 1/sqrt(128)
  const int GEMM_BLKS = GB0 + GB1 + GB2;
  const int EDGE_BLKS = (NTOT * 16 + 255) / 256;

  for (int l = 0; l < 2; ++l) {
    const f16* Xin = (l == 0) ? XsA : XsB;
    k_gemm3<<<GEMM_BLKS, 256, 0, stream>>>(Xin, WtHi, WtLo, qkv_b, bkeff6, QV, Kb, l);
    if (l == 0)
      k_edge<0><<<EDGE_BLKS, 256, 0, stream>>>(rowptr, srcs, QV, Kb, XsB,
                                               (float*)nullptr, scale);
    else
      k_edge<1><<<EDGE_BLKS, 256, 0, stream>>>(rowptr, srcs, QV, Kb,
                                               (f16*)nullptr, out, scale);
  }
}

// Round 11
// 436.026 us; speedup vs baseline: 1.0872x; 1.0872x over previous
//
#include <hip/hip_runtime.h>

#define NP 50000
#define NU 100000
#define NS 20000
#define NTOT 170000
#define E0 400000
#define E1 300000
#define E2 300000

typedef _Float16 f16;
typedef __attribute__((ext_vector_type(8))) _Float16 half8;
typedef __attribute__((ext_vector_type(4))) _Float16 half4;
typedef __attribute__((ext_vector_type(4))) float f32x4;
typedef unsigned int uint32;

// ---------------------------------------------------------------------------
// fused init v2: block = 64 nodes (type-pure ranges), thread = 4 dims x 8
// nodes; lin_w held in registers (20 x float4), x staged via LDS (broadcast).
// ---------------------------------------------------------------------------
#define IB0 782    // ceil(NP/64)
#define IB1 1563   // ceil(NU/64)
#define IB2 313    // ceil(NS/64)
__global__ __launch_bounds__(256) void k_init_all(
    const float* __restrict__ xp, const float* __restrict__ xu,
    const float* __restrict__ xs, const int* __restrict__ nidp,
    const int* __restrict__ nidu, const int* __restrict__ nids,
    const float* __restrict__ lin_w, const float* __restrict__ lin_b,
    const float* __restrict__ embp, const float* __restrict__ embu,
    const float* __restrict__ embs, f16* __restrict__ xb) {
  __shared__ float xl[64 * 20];  // 5 KB
  int bid = blockIdx.x, tid = threadIdx.x;
  int t, base, M, goff;
  const float* x;
  const int* nid;
  const float* emb;
  if (bid < IB0) { t = 0; base = bid * 64; M = NP; goff = 0; x = xp; nid = nidp; emb = embp; }
  else if (bid < IB0 + IB1) { t = 1; base = (bid - IB0) * 64; M = NU; goff = NP; x = xu; nid = nidu; emb = embu; }
  else { t = 2; base = (bid - IB0 - IB1) * 64; M = NS; goff = NP + NU; x = xs; nid = nids; emb = embs; }

  // stage x rows for the block's 64 nodes
#pragma unroll
  for (int i = 0; i < 5; ++i) {
    int idx = i * 256 + tid;  // 0..1279
    int nn = idx / 20, jj = idx - nn * 20;
    int gn = base + nn;
    if (gn >= M) gn = M - 1;
    xl[idx] = x[gn * 20 + jj];
  }
  __syncthreads();

  int dg = tid & 31, ns = tid >> 5;
  int d = dg * 4;
  const float* lw = lin_w + t * 20 * 128 + d;
  float4 w[20];
#pragma unroll
  for (int j = 0; j < 20; ++j) w[j] = *(const float4*)(lw + j * 128);
  float4 bb = *(const float4*)&lin_b[t * 128 + d];

#pragma unroll 2
  for (int i = 0; i < 8; ++i) {
    int ln = i * 8 + ns;
    int gn = base + ln;
    bool ok = gn < M;
    int gnc = ok ? gn : M - 1;
    float4 s = *(const float4*)&emb[(size_t)nid[gnc] * 128 + d];
    s.x += bb.x; s.y += bb.y; s.z += bb.z; s.w += bb.w;
#pragma unroll
    for (int j = 0; j < 20; ++j) {
      float xj = xl[ln * 20 + j];
      s.x += xj * w[j].x; s.y += xj * w[j].y; s.z += xj * w[j].z; s.w += xj * w[j].w;
    }
    if (ok) {
      half4 o;
      o[0] = (f16)s.x; o[1] = (f16)s.y; o[2] = (f16)s.z; o[3] = (f16)s.w;
      *(half4*)(xb + (size_t)(goff + gn) * 128 + d) = o;
    }
  }
}

// ---------------------------------------------------------------------------
// batched Keff: y = l*3+t.  Keff[y][c][d] = sum_f Wk[c][f] * We[d][f]
// ---------------------------------------------------------------------------
__global__ __launch_bounds__(128) void k_keff(const float* __restrict__ qkv_w,
                                              const float* __restrict__ qkv_b,
                                              const float* __restrict__ W_edge,
                                              float* __restrict__ Keff,
                                              float* __restrict__ bkeff) {
  int y = blockIdx.y;  // l*3 + t
  int l = y / 3, t = y - l * 3;
  int et = (t == 0) ? 0 : (t == 1) ? 2 : 1;  // edge type with dst == t
  const float* Wk = qkv_w + (size_t)(y * 3 + 1) * 16384;
  const float* bk = qkv_b + (size_t)(y * 3 + 1) * 128;
  const float* We = W_edge + (size_t)(l * 3 + et) * 16384;
  float* Ko = Keff + (size_t)y * 16384;
  float* bo = bkeff + (size_t)y * 128;

  __shared__ float Wes[128][65];
  int c = blockIdx.x, tid = threadIdx.x;
  float s = 0.f, tb = 0.f;
  for (int f0 = 0; f0 < 128; f0 += 64) {
    __syncthreads();
    int fr = tid & 63, r0 = tid >> 6;
    for (int it = 0; it < 64; ++it) {
      int row = it * 2 + r0;
      Wes[row][fr] = We[row * 128 + f0 + fr];
    }
    __syncthreads();
#pragma unroll 16
    for (int fp = 0; fp < 64; ++fp) s += Wk[c * 128 + f0 + fp] * Wes[tid][fp];
    if (c == 0) {
      for (int fp = 0; fp < 64; ++fp) tb += bk[f0 + fp] * Wes[tid][fp];
    }
  }
  Ko[c * 128 + tid] = s;
  if (c == 0) bo[tid] = tb;
}

// ---------------------------------------------------------------------------
// split+transpose all 18 weights (f16 hi/lo) in one launch.
// ---------------------------------------------------------------------------
__global__ __launch_bounds__(256) void k_splitw18(const float* __restrict__ qkv_w,
                                                  const float* __restrict__ Keff6,
                                                  f16* __restrict__ hi,
                                                  f16* __restrict__ lo) {
  int slot = blockIdx.y;
  int y = slot / 3, r = slot - y * 3;
  const float* src = (r == 1) ? (Keff6 + (size_t)y * 16384)
                              : (qkv_w + (size_t)(y * 3 + ((r == 0) ? 0 : 2)) * 16384);
  f16* h = hi + (size_t)slot * 16384;
  f16* l = lo + (size_t)slot * 16384;
  int idx = blockIdx.x * 256 + threadIdx.x;  // 0..16383
  int n = idx >> 7, c = idx & 127;
  float f = src[c * 128 + n];
  f16 hb = (f16)f;
  h[idx] = hb;
  l[idx] = (f16)(f - (float)hb);
}

// ---------------------------------------------------------------------------
// Triple-B MFMA GEMM (f16), 64-row tiles, all 3 types in one launch.
// hi+lo split kept only for K (=Keff, two-weight product); Q/V use hi only.
// LDS-staged A (swizzled) + LDS-staged epilogue (full-line stores).
// ---------------------------------------------------------------------------
#define GB0 782    // ceil(NP/64)
#define GB1 1563   // ceil(NU/64)
#define GB2 313    // ceil(NS/64)
__global__ __launch_bounds__(256, 4) void k_gemm3(
    const f16* __restrict__ Xin,
    const f16* __restrict__ WtHi, const f16* __restrict__ WtLo,
    const float* __restrict__ qkv_b, const float* __restrict__ bkeff6,
    f16* __restrict__ QV, f16* __restrict__ Kb, int l) {
  __shared__ f16 As[64 * 128];  // 16 KB
  __shared__ f16 Ys[64 * 128];  // 16 KB output staging
  int bid = blockIdx.x;
  int t, row0, M, moff;
  if (bid < GB0) { t = 0; row0 = bid * 64; M = NP; moff = 0; }
  else if (bid < GB0 + GB1) { t = 1; row0 = (bid - GB0) * 64; M = NU; moff = NP; }
  else { t = 2; row0 = (bid - GB0 - GB1) * 64; M = NS; moff = NP + NU; }
  int y = l * 3 + t;
  const f16* A = Xin + (size_t)moff * 128;
  const f16* Whi = WtHi + (size_t)y * 3 * 16384;
  const f16* Wlo = WtLo + (size_t)y * 3 * 16384;

  int tid = threadIdx.x;
  int wave = tid >> 6, lane = tid & 63;
  int colw = wave * 32;
  int lrow = lane & 15, kgrp = lane >> 4;

  // ---- stage A tile: linear global read, swizzled LDS write ----
#pragma unroll
  for (int i = 0; i < 4; ++i) {
    int chunkLin = i * 256 + tid;  // 0..1023
    int row = chunkLin >> 4;
    int chunk = chunkLin & 15;
    int grow = row0 + row;
    if (grow >= M) grow = M - 1;
    half8 v = *(const half8*)(A + (size_t)grow * 128 + chunk * 8);
    *(half8*)(As + row * 128 + (chunk ^ (row & 7)) * 8) = v;
  }
  __syncthreads();

  int x7 = lrow & 7;

#pragma unroll
  for (int bw = 0; bw < 3; ++bw) {
    f32x4 acc[4][2] = {};
#pragma unroll
    for (int s = 0; s < 4; ++s) {
      half8 bh[2], bl[2];
#pragma unroll
      for (int nt = 0; nt < 2; ++nt) {
        int col = colw + nt * 16 + lrow;
        size_t boff = (size_t)bw * 16384 + col * 128 + s * 32 + kgrp * 8;
        bh[nt] = *(const half8*)(Whi + boff);
        if (bw == 1) bl[nt] = *(const half8*)(Wlo + boff);
      }
      int c2 = (s * 4 + kgrp) ^ x7;
#pragma unroll
      for (int mt = 0; mt < 4; ++mt) {
        int row = mt * 16 + lrow;
        half8 a = *(const half8*)(As + row * 128 + c2 * 8);
        acc[mt][0] = __builtin_amdgcn_mfma_f32_16x16x32_f16(a, bh[0], acc[mt][0], 0, 0, 0);
        acc[mt][1] = __builtin_amdgcn_mfma_f32_16x16x32_f16(a, bh[1], acc[mt][1], 0, 0, 0);
        if (bw == 1) {
          acc[mt][0] = __builtin_amdgcn_mfma_f32_16x16x32_f16(a, bl[0], acc[mt][0], 0, 0, 0);
          acc[mt][1] = __builtin_amdgcn_mfma_f32_16x16x32_f16(a, bl[1], acc[mt][1], 0, 0, 0);
        }
      }
    }
    // ---- epilogue: stage through LDS (swizzled), stream full lines ----
    const float* bias = (bw == 0) ? (qkv_b + (size_t)(y * 3 + 0) * 128)
                      : (bw == 1) ? (bkeff6 + (size_t)y * 128)
                                  : (qkv_b + (size_t)(y * 3 + 2) * 128);
    f16* Ybase = (bw == 1) ? Kb : (QV + ((bw == 2) ? 128 : 0));
    int RS = (bw == 1) ? 128 : 256;
    float b0 = bias[colw + lrow];
    float b1 = bias[colw + 16 + lrow];
    int col0i = colw + lrow;
    int col1i = colw + 16 + lrow;
    __syncthreads();
#pragma unroll
    for (int mt = 0; mt < 4; ++mt) {
#pragma unroll
      for (int r = 0; r < 4; ++r) {
        int lr = mt * 16 + kgrp * 4 + r;
        int sw = lr & 7;
        Ys[lr * 128 + (((col0i >> 3) ^ sw) * 8) + (col0i & 7)] = (f16)(acc[mt][0][r] + b0);
        Ys[lr * 128 + (((col1i >> 3) ^ sw) * 8) + (col1i & 7)] = (f16)(acc[mt][1][r] + b1);
      }
    }
    __syncthreads();
#pragma unroll
    for (int i = 0; i < 4; ++i) {
      int chunk = i * 256 + tid;  // 0..1023
      int row = chunk >> 4, c = chunk & 15;
      int grow = row0 + row;
      if (grow < M)
        *(half8*)(Ybase + (size_t)(moff + grow) * RS + c * 8) =
            *(const half8*)(Ys + row * 128 + ((c ^ (row & 7)) * 8));
    }
  }
}

// ---------------------------------------------------------------------------
// FUSED edge kernel: 16 lanes per dst row (4 rows/wave), 8 dims/lane,
// edges serial with depth-1 prefetch (round-9 variant: lowest VGPR, at the
// measured random-gather BW ceiling ~4 TB/s).
// ---------------------------------------------------------------------------
template <int MODE>
__global__ __launch_bounds__(256) void k_edge(
    const int* __restrict__ rowptr, const int* __restrict__ srcs,
    const f16* __restrict__ QV, const f16* __restrict__ Kb,
    f16* __restrict__ obf, float* __restrict__ of, float scale) {
  int gid = blockIdx.x * 256 + threadIdx.x;
  int wid = gid >> 4;  // dst row, one per 16-lane group
  if (wid >= NTOT) return;
  int sub = threadIdx.x & 15;  // dims sub*8 .. sub*8+7
  int dstNode, srcBase;
  if (wid < NP) { dstNode = wid; srcBase = NP; }
  else if (wid < NP + NS) { dstNode = wid + 100000; srcBase = 0; }
  else { dstNode = wid - NS; srcBase = NP + NU; }

  int s0 = rowptr[wid], s1 = rowptr[wid + 1];

  float kf[8];
  {
    half8 kh = *(const half8*)(Kb + (size_t)dstNode * 128 + sub * 8);
#pragma unroll
    for (int j = 0; j < 8; ++j) kf[j] = (float)kh[j];
  }

  float acc[8] = {};
  float dsum = 0.f;
  int k = s0;
  half8 qN, vN;
  if (k < s1) {
    const f16* qv = QV + (size_t)(srcBase + srcs[k]) * 256 + sub * 8;
    qN = *(const half8*)qv;
    vN = *(const half8*)(qv + 128);
  }
  while (k < s1) {
    half8 qh = qN, vh = vN;
    int kn = k + 1;
    if (kn < s1) {
      const f16* qv = QV + (size_t)(srcBase + srcs[kn]) * 256 + sub * 8;
      qN = *(const half8*)qv;
      vN = *(const half8*)(qv + 128);
    }
    float p = 0.f;
#pragma unroll
    for (int j = 0; j < 8; ++j) p = fmaf((float)qh[j], kf[j], p);
    p += __shfl_xor(p, 8, 16);
    p += __shfl_xor(p, 4, 16);
    p += __shfl_xor(p, 2, 16);
    p += __shfl_xor(p, 1, 16);
    float s = p * scale;
    s = (s > 0.f) ? s : 0.01f * s;
    float e = __expf(s);
    dsum += e;
#pragma unroll
    for (int j = 0; j < 8; ++j) acc[j] = fmaf((float)vh[j], e, acc[j]);
    k = kn;
  }

  float inv = (s1 > s0) ? 1.f / dsum : 0.f;

  if (MODE == 0) {
    half8 o;
#pragma unroll
    for (int j = 0; j < 8; ++j) o[j] = (f16)fmaxf(acc[j] * inv, 0.f);
    *(half8*)(obf + (size_t)dstNode * 128 + sub * 8) = o;
  } else {
    float4 w0, w1;
    w0.x = acc[0] * inv; w0.y = acc[1] * inv; w0.z = acc[2] * inv; w0.w = acc[3] * inv;
    w1.x = acc[4] * inv; w1.y = acc[5] * inv; w1.z = acc[6] * inv; w1.w = acc[7] * inv;
    float* orow = of + (size_t)dstNode * 128 + sub * 8;
    *(float4*)orow = w0;
    *(float4*)(orow + 4) = w1;
  }
}

// ---------------------------------------------------------------------------
// global CSR build over all 3 edge types
// ---------------------------------------------------------------------------
__global__ void k_count_all(const int* __restrict__ e0, const int* __restrict__ e1,
                            const int* __restrict__ e2, int* __restrict__ cnt) {
  int e = blockIdx.x * 256 + threadIdx.x;
  if (e < E0) atomicAdd(&cnt[e0[E0 + e]], 1);
  else if (e < E0 + E1) atomicAdd(&cnt[NP + e1[E1 + (e - E0)]], 1);
  else if (e < E0 + E1 + E2) atomicAdd(&cnt[NP + NS + e2[E2 + (e - E0 - E1)]], 1);
}

__global__ void k_fill_all(const int* __restrict__ e0, const int* __restrict__ e1,
                           const int* __restrict__ e2, const int* __restrict__ rowptr,
                           int* __restrict__ cur, int* __restrict__ srcs) {
  int e = blockIdx.x * 256 + threadIdx.x;
  int row, src;
  if (e < E0) { row = e0[E0 + e]; src = e0[e]; }
  else if (e < E0 + E1) { row = NP + e1[E1 + (e - E0)]; src = e1[e - E0]; }
  else if (e < E0 + E1 + E2) { row = NP + NS + e2[E2 + (e - E0 - E1)]; src = e2[e - E0 - E1]; }
  else return;
  int p = atomicAdd(&cur[row], 1);
  srcs[rowptr[row] + p] = src;
}

__global__ __launch_bounds__(256) void k_blocksum(const int* __restrict__ c, int N,
                                                  int* __restrict__ bs) {
  int base = blockIdx.x * 1024;
  int t = threadIdx.x;
  int s = 0;
#pragma unroll
  for (int j = 0; j < 4; ++j) {
    int i = base + t * 4 + j;
    if (i < N) s += c[i];
  }
#pragma unroll
  for (int off = 32; off; off >>= 1) s += __shfl_down(s, off, 64);
  __shared__ int wsm[4];
  if ((t & 63) == 0) wsm[t >> 6] = s;
  __syncthreads();
  if (t == 0) bs[blockIdx.x] = wsm[0] + wsm[1] + wsm[2] + wsm[3];
}

__global__ __launch_bounds__(256) void k_scan_bsums(int* __restrict__ bs, int nb) {
  __shared__ int sm[256];
  int t = threadIdx.x;
  int v[4];
  int s = 0;
#pragma unroll
  for (int j = 0; j < 4; ++j) {
    int i = t * 4 + j;
    v[j] = (i < nb) ? bs[i] : 0;
    s += v[j];
  }
  sm[t] = s;
  __syncthreads();
  for (int off = 1; off < 256; off <<= 1) {
    int x = (t >= off) ? sm[t - off] : 0;
    __syncthreads();
    sm[t] += x;
    __syncthreads();
  }
  int run = t ? sm[t - 1] : 0;
#pragma unroll
  for (int j = 0; j < 4; ++j) {
    int i = t * 4 + j;
    if (i < nb) {
      int tmp = v[j];
      bs[i] = run;
      run += tmp;
    }
  }
}

__global__ __launch_bounds__(256) void k_scan_apply(const int* __restrict__ c,
                                                    const int* __restrict__ bofs,
                                                    int* __restrict__ rowptr, int N) {
  __shared__ int sm[256];
  int base = blockIdx.x * 1024, t = threadIdx.x;
  int v[4];
  int s = 0;
#pragma unroll
  for (int j = 0; j < 4; ++j) {
    int i = base + t * 4 + j;
    v[j] = (i < N) ? c[i] : 0;
    s += v[j];
  }
  sm[t] = s;
  __syncthreads();
  for (int off = 1; off < 256; off <<= 1) {
    int x = (t >= off) ? sm[t - off] : 0;
    __syncthreads();
    sm[t] += x;
    __syncthreads();
  }
  int run = bofs[blockIdx.x] + (t ? sm[t - 1] : 0);
#pragma unroll
  for (int j = 0; j < 4; ++j) {
    int i = base + t * 4 + j;
    if (i < N) {
      run += v[j];
      rowptr[i + 1] = run;
    }
  }
  if (blockIdx.x == 0 && t == 0) rowptr[0] = 0;
}

// ---------------------------------------------------------------------------

extern "C" void kernel_launch(void* const* d_in, const int* in_sizes, int n_in,
                              void* d_out, int out_size, void* d_ws, size_t ws_size,
                              hipStream_t stream) {
  const float* x_in[3] = {(const float*)d_in[0], (const float*)d_in[1], (const float*)d_in[2]};
  const int* nid[3] = {(const int*)d_in[3], (const int*)d_in[4], (const int*)d_in[5]};
  const int* ei[3] = {(const int*)d_in[6], (const int*)d_in[7], (const int*)d_in[8]};
  const float* lin_w = (const float*)d_in[9];
  const float* lin_b = (const float*)d_in[10];
  const float* emb[3] = {(const float*)d_in[11], (const float*)d_in[12], (const float*)d_in[13]};
  const float* qkv_w = (const float*)d_in[14];
  const float* qkv_b = (const float*)d_in[15];
  const float* W_edge = (const float*)d_in[16];
  float* out = (float*)d_out;

  char* ws = (char*)d_ws;
  size_t o = 0;
  auto carve = [&](size_t bytes) {
    char* p = ws + o;
    o = (o + bytes + 255) & ~(size_t)255;
    return p;
  };
  f16* XsA = (f16*)carve((size_t)NTOT * 128 * 2);
  f16* XsB = (f16*)carve((size_t)NTOT * 128 * 2);
  f16* QV = (f16*)carve((size_t)NTOT * 256 * 2);   // interleaved [Q|V] per node
  f16* Kb = (f16*)carve((size_t)NTOT * 128 * 2);
  float* Keff6 = (float*)carve((size_t)6 * 16384 * 4);
  float* bkeff6 = (float*)carve(6 * 128 * 4);
  f16* WtHi = (f16*)carve((size_t)18 * 16384 * 2);
  f16* WtLo = (f16*)carve((size_t)18 * 16384 * 2);
  int* cnt = (int*)carve((size_t)2 * NTOT * 4);  // cnt + cursor, one memset
  int* cur = cnt + NTOT;
  int* bsums = (int*)carve(1024 * 4);
  int* rowptr = (int*)carve((NTOT + 1) * 4);
  int* srcs = (int*)carve((size_t)(E0 + E1 + E2) * 4);
  (void)ws_size;

  // ---- initial features (single launch, w-amortized) ----
  k_init_all<<<IB0 + IB1 + IB2, 256, 0, stream>>>(
      x_in[0], x_in[1], x_in[2], nid[0], nid[1], nid[2], lin_w, lin_b, emb[0],
      emb[1], emb[2], XsA);

  // ---- global CSR over all edge types ----
  {
    const int ETOT = E0 + E1 + E2;
    int nb = (NTOT + 1023) / 1024;
    hipMemsetAsync(cnt, 0, (size_t)2 * NTOT * 4, stream);
    k_count_all<<<(ETOT + 255) / 256, 256, 0, stream>>>(ei[0], ei[1], ei[2], cnt);
    k_blocksum<<<nb, 256, 0, stream>>>(cnt, NTOT, bsums);
    k_scan_bsums<<<1, 256, 0, stream>>>(bsums, nb);
    k_scan_apply<<<nb, 256, 0, stream>>>(cnt, bsums, rowptr, NTOT);
    k_fill_all<<<(ETOT + 255) / 256, 256, 0, stream>>>(ei[0], ei[1], ei[2], rowptr, cur,
                                                       srcs);
  }

  // ---- weight prep (both layers) ----
  {
    dim3 gk(128, 6);
    k_keff<<<gk, 128, 0, stream>>>(qkv_w, qkv_b, W_edge, Keff6, bkeff6);
    dim3 gs(64, 18);
    k_splitw18<<<gs, 256, 0, stream>>>(qkv_w, Keff6, WtHi, WtLo);
  }

  const float scale = 0.08838834764831845f;  // 1/sqrt(128)
  const int GEMM_BLKS = GB0 + GB1 + GB2;
  const int EDGE_BLKS = (NTOT * 16 + 255) / 256;

  for (int l = 0; l < 2; ++l) {
    const f16* Xin = (l == 0) ? XsA : XsB;
    k_gemm3<<<GEMM_BLKS, 256, 0, stream>>>(Xin, WtHi, WtLo, qkv_b, bkeff6, QV, Kb, l);
    if (l == 0)
      k_edge<0><<<EDGE_BLKS, 256, 0, stream>>>(rowptr, srcs, QV, Kb, XsB,
                                               (float*)nullptr, scale);
    else
      k_edge<1><<<EDGE_BLKS, 256, 0, stream>>>(rowptr, srcs, QV, Kb,
                                               (f16*)nullptr, out, scale);
  }
}